// Round 7
// baseline (1930.049 us; speedup 1.0000x reference)
//
#include <hip/hip_runtime.h>

typedef unsigned short u16;
typedef unsigned int u32;
typedef __attribute__((ext_vector_type(8))) short short8;
typedef __attribute__((ext_vector_type(4))) float f32x4;

constexpr int CB = 64, CT = 512, CX = 8, CH = 128;

__device__ __forceinline__ u16 f2b(float f) {
  u32 u = __float_as_uint(f);
  return (u16)((u + 0x7FFFu + ((u >> 16) & 1u)) >> 16);  // RNE bf16
}
__device__ __forceinline__ float sigf(float x) {
  return __fdividef(1.0f, 1.0f + __expf(-x));
}
__device__ __forceinline__ float tanhfast(float x) {
  return 1.0f - __fdividef(2.0f, __expf(2.0f * x) + 1.0f);
}
__device__ __forceinline__ f32x4 mfma16(short8 a, short8 b, f32x4 c) {
  return __builtin_amdgcn_mfma_f32_16x16x32_bf16(a, b, c, 0, 0, 0);
}

// LDS-only barrier: publishes LDS writes WITHOUT the vmcnt(0) drain
// __syncthreads() emits; global loads/stores stay in flight across it.
__device__ __forceinline__ void barrier_lgkm() {
  asm volatile("s_waitcnt lgkmcnt(0)" ::: "memory");
  __builtin_amdgcn_s_barrier();
  asm volatile("" ::: "memory");
}

// v1 counted barrier (R5-proven): >=9 vmem ops/iter -> vmcnt(8) makes iter
// t-1's stores L2-visible while iter t's ops stay in flight.
__device__ __forceinline__ void barrier_vm8() {
  asm volatile("s_waitcnt vmcnt(8) lgkmcnt(0)" ::: "memory");
  __builtin_amdgcn_s_barrier();
  asm volatile("" ::: "memory");
}

// v2 counted barrier. Guaranteed VMEM ops per scan_v2 iteration (per wave,
// all between consecutive barrier C's thanks to the asm memory clobbers):
// 4 af_g (dwordx4, lane-varying) + 4 cg + 4 gt/awi + 12 wiw + 1 src-lane
// = 25 loads (all lane-varying addresses -> cannot scalarize) + 3 stores
// (exec-masked qd==0, every wave has qd==0 lanes -> always issue) = 28.
// vmcnt(20) forces completion of everything except the 20 newest ops:
// with 28 ops issued this iteration, ALL of iteration t-1's ops (incl. its
// 3 stores) are forced complete -- safe even if several loads were merged
// or scalarized (margin of 8). The forced 8 oldest current-iter loads were
// issued ~a full stage earlier (L2/L3-resident) -> no stall. Next-iter
// global gathers touch rows <= t-2 only (2-deep hbuf/cbuf ping-pong covers
// t-1, t-2), so "iter t-1 stores visible" is exactly the required invariant.
__device__ __forceinline__ void barrier_vm20() {
  asm volatile("s_waitcnt vmcnt(20) lgkmcnt(0)" ::: "memory");
  __builtin_amdgcn_s_barrier();
  asm volatile("" ::: "memory");
}

// ---------------- ws layout (bytes) ----------------
// common:
// 0         : WgwT  bf16 [384][256]  B^T of [w_hh_w; w_ih_w]   (196608)
// 196608    : WahcT bf16 [512][128]  B^T of [a_hh | w_hh_c]    (131072)
// 327680    : WcaT  bf16 [512][128]  B^T of [w_ih_c | a_ih]    (131072)
// 458752    : wica  f32  [B*T][512]  [wi_c_all | a_wi_all]     (67108864)
// v2 (needs 478609408 B total):
// 67567616  : wiw   f32  [B*T*X][384]  skip_words @ w_ih_w     (402653184)
// 470220800 : hsb16 bf16 [B][T][128]   bf16 mirror of hs       (8388608)
// v1 fallback (needs 134676480 B total):
// 67567616  : swb16 bf16 [B][T][X][128] skip_words pre-cast    (67108864)

__global__ void prep_kernel(const float* __restrict__ w_ih_c, const float* __restrict__ w_hh_c,
                            const float* __restrict__ a_ih, const float* __restrict__ a_hh,
                            const float* __restrict__ w_ih_w, const float* __restrict__ w_hh_w,
                            u16* __restrict__ WgwT, u16* __restrict__ WahcT, u16* __restrict__ WcaT) {
  int gid = blockIdx.x * blockDim.x + threadIdx.x;  // 224*1024 = 229376
  if (gid < 98304) {                 // WgwT[n][k], n<384, k<256
    int n = gid >> 8, k = gid & 255;
    float v = (k < 128) ? w_hh_w[k * 384 + n] : w_ih_w[(k - 128) * 384 + n];
    WgwT[gid] = f2b(v);
  } else if (gid < 163840) {         // WahcT[n][k], n<512, k<128
    int i = gid - 98304; int n = i >> 7, k = i & 127;
    float v = (n < 128) ? a_hh[k * 128 + n] : w_hh_c[k * 384 + (n - 128)];
    WahcT[i] = f2b(v);
  } else if (gid < 229376) {         // WcaT[n][k], n<512, k<128
    int i = gid - 163840; int n = i >> 7, k = i & 127;
    float v = (n < 384) ? w_ih_c[k * 384 + n] : a_ih[k * 128 + (n - 384)];
    WcaT[i] = f2b(v);
  }
}

// v1 only: skip_words f32 -> bf16
__global__ void prep_sw_kernel(const float* __restrict__ sw, u16* __restrict__ swb16) {
  size_t i = ((size_t)blockIdx.x * 1024 + threadIdx.x) * 8;
  float4 x0 = *(const float4*)(sw + i);
  float4 x1 = *(const float4*)(sw + i + 4);
  short8 o;
  o[0] = (short)f2b(x0.x); o[1] = (short)f2b(x0.y); o[2] = (short)f2b(x0.z); o[3] = (short)f2b(x0.w);
  o[4] = (short)f2b(x1.x); o[5] = (short)f2b(x1.y); o[6] = (short)f2b(x1.z); o[7] = (short)f2b(x1.w);
  *(short8*)(swb16 + i) = o;
}

// wica[m][n] = inp @ [w_ih_c | a_ih] + bias, m = b*T+t, N=512, K=128
__global__ __launch_bounds__(256) void proj_kernel(const float* __restrict__ inp,
    const u16* __restrict__ WcaT, const float* __restrict__ bias_c,
    const float* __restrict__ a_bias, float* __restrict__ wica) {
  const int m0 = blockIdx.x * 64;
  const int wv = threadIdx.x >> 6, ln = threadIdx.x & 63;
  const int l16 = ln & 15, qd = ln >> 4;
  const int arow = m0 + wv * 16 + l16;
  short8 af[4];
#pragma unroll
  for (int kt = 0; kt < 4; ++kt) {
    const float* p = inp + (size_t)arow * 128 + kt * 32 + qd * 8;
    float4 x0 = *(const float4*)p;
    float4 x1 = *(const float4*)(p + 4);
    short8 a;
    a[0] = (short)f2b(x0.x); a[1] = (short)f2b(x0.y); a[2] = (short)f2b(x0.z); a[3] = (short)f2b(x0.w);
    a[4] = (short)f2b(x1.x); a[5] = (short)f2b(x1.y); a[6] = (short)f2b(x1.z); a[7] = (short)f2b(x1.w);
    af[kt] = a;
  }
  for (int nt = 0; nt < 32; ++nt) {
    const int col = nt * 16 + l16;
    f32x4 acc = {0.f, 0.f, 0.f, 0.f};
#pragma unroll
    for (int kt = 0; kt < 4; ++kt) {
      short8 bf = *(const short8*)(WcaT + (size_t)col * 128 + kt * 32 + qd * 8);
      acc = mfma16(af[kt], bf, acc);
    }
    const float bias = (col < 384) ? bias_c[col] : a_bias[col - 384];
#pragma unroll
    for (int r = 0; r < 4; ++r) {
      const int orow = m0 + wv * 16 + qd * 4 + r;
      wica[(size_t)orow * 512 + col] = acc[r] + bias;
    }
  }
}

// v2 prep: wiw[m][n] = skip_words[m][:] @ w_ih_w, m=(b*T+t)*X+x (262144 rows),
// N=384, K=128. B-operand = WgwT[n][128+k] (the w_ih_w^T slice). fp32 out ->
// identical arithmetic to computing this inside the scan (bf16 products,
// fp32 accumulation), so absmax is unchanged vs R5.
__global__ __launch_bounds__(256) void wiw_kernel(const float* __restrict__ skw,
    const u16* __restrict__ WgwT, float* __restrict__ wiw) {
  const int m0 = blockIdx.x * 64;
  const int wv = threadIdx.x >> 6, ln = threadIdx.x & 63;
  const int l16 = ln & 15, qd = ln >> 4;
  const int arow = m0 + wv * 16 + l16;
  short8 af[4];
#pragma unroll
  for (int kt = 0; kt < 4; ++kt) {
    const float* p = skw + (size_t)arow * 128 + kt * 32 + qd * 8;
    float4 x0 = *(const float4*)p;
    float4 x1 = *(const float4*)(p + 4);
    short8 a;
    a[0] = (short)f2b(x0.x); a[1] = (short)f2b(x0.y); a[2] = (short)f2b(x0.z); a[3] = (short)f2b(x0.w);
    a[4] = (short)f2b(x1.x); a[5] = (short)f2b(x1.y); a[6] = (short)f2b(x1.z); a[7] = (short)f2b(x1.w);
    af[kt] = a;
  }
  for (int nt = 0; nt < 24; ++nt) {
    const int col = nt * 16 + l16;
    f32x4 acc = {0.f, 0.f, 0.f, 0.f};
#pragma unroll
    for (int kt = 0; kt < 4; ++kt) {
      short8 bf = *(const short8*)(WgwT + (size_t)col * 256 + 128 + kt * 32 + qd * 8);
      acc = mfma16(af[kt], bf, acc);
    }
#pragma unroll
    for (int r = 0; r < 4; ++r) {
      const int orow = m0 + wv * 16 + qd * 4 + r;
      wiw[(size_t)orow * 384 + col] = acc[r];
    }
  }
}

// ===================== scan_v2: 2 barriers/step, reg A-frags ================
// Latency-bound redesign (R5 counters: MfmaUtil 4.4 / VALU 12.9 / 7200cy/step
// with ~1200cy issue). Changes vs R5:
//  - sw-projection hoisted to wiw_kernel: -12 MFMA/step, -64 frag VGPRs.
//  - A-fragment built in REGISTERS per lane: bf16 gathers from hsb16 in
//    fragment layout, fresh rows selected from broadcast hbuf/cbuf reads.
//    Deletes Asg/Csg/gca and barrier A: 2 barriers/step instead of 3.
//  - gc via Psg row 8 + stage-5 e-chains (= round-0 HW-proven mapping).
__global__ __launch_bounds__(512, 2) void scan_v2(
    const int* __restrict__ srcp,          // [B][T][X]
    const int* __restrict__ cntp,          // [B][T]
    const float* __restrict__ bias_w,      // [384]
    const u16* __restrict__ WgwT,          // [384][256]
    const u16* __restrict__ WahcT,         // [512][128]
    const float* __restrict__ wica,        // [B*T][512]
    const float* __restrict__ wiw,         // [B*T*X][384]
    u16* __restrict__ hsb16,               // [B][T][128] bf16 mirror of hs
    float* __restrict__ out)               // hs [B][T][128] ; cs follows
{
  const int b = blockIdx.x;
  const int tid = threadIdx.x;
  const int wv = tid >> 6, ln = tid & 63, l16 = ln & 15, qd = ln >> 4;
  const int h = wv * 16 + l16;
  const int row = l16 & 7;   // A-matrix slot owned by this lane (dup l16>=8)

  float* hs = out + (size_t)b * CT * CH;
  float* cs = out + (size_t)(CB + b) * CT * CH;
  u16* hsb = hsb16 + (size_t)b * CT * CH;
  const int* srcb = srcp + b * CT * CX;
  const int* cntb = cntp + b * CT;
  const float* wicab = wica + (size_t)b * CT * 512;
  const float* wiwb = wiw + (size_t)b * CT * CX * 384;

  // LDS: ~6 KB total
  __shared__ __align__(16) u16 Psg[16 * 136];   // rows 0..7 c1_skip; 8 h0; 9..15 zero
  __shared__ __align__(16) u16 hbuf[2][128];    // bf16 h ping-pong: h_t -> hbuf[t&1]
  __shared__ __align__(16) float cbuf[2][128];  // fp32 c ping-pong

  for (int i = tid; i < 16 * 136; i += 512) Psg[i] = 0;
  if (tid < 128) {
    hbuf[0][tid] = 0; hbuf[1][tid] = 0;
    cbuf[0][tid] = 0.0f; cbuf[1][tid] = 0.0f;
  }

  // persistent B-fragments: 28 short8 = 112 regs (fits with AGPR room)
  short8 wgwf[3][4];  // w_hh_w gate cols g*128+h, K=128 (h-part only)
#pragma unroll
  for (int g = 0; g < 3; ++g)
#pragma unroll
    for (int kt = 0; kt < 4; ++kt)
      wgwf[g][kt] = *(const short8*)(WgwT + (size_t)(g * 128 + h) * 256 + kt * 32 + qd * 8);
  short8 wacf[4][4];  // j=0: a_hh col h ; j=1..3: w_hh_c gate cols
#pragma unroll
  for (int j = 0; j < 4; ++j)
#pragma unroll
    for (int kt = 0; kt < 4; ++kt)
      wacf[j][kt] = *(const short8*)(WahcT + (size_t)(j * 128 + h) * 128 + kt * 32 + qd * 8);
  const float bw0 = bias_w[h], bw1 = bias_w[128 + h], bw2 = bias_w[256 + h];

  // prologue prefetch for t=0 ----------------------------------------------
  int sl_c = srcb[row];            // per-lane src of own slot, step t
  int sl_n = srcb[CX + row];       // step t+1
  int cnt_c = cntb[0], cnt_n = cntb[1];
  short8 af_g[4];                  // global A-frag candidate (poison at t=0, masked)
#pragma unroll
  for (int kt = 0; kt < 4; ++kt)
    af_g[kt] = *(const short8*)(hsb + (size_t)sl_c * CH + kt * 32 + qd * 8);
  float cg[4];                     // global c_x candidates for rows qd*4+r
#pragma unroll
  for (int r = 0; r < 4; ++r) {
    int sr = __shfl(sl_c, (qd * 4 + r) & 7, 64);
    cg[r] = cs[(size_t)sr * CH + h];
  }
  float gt0 = wicab[h], gt1 = wicab[128 + h], gt2 = wicab[256 + h], awi = wicab[384 + h];
  float ww0[4], ww1[4], ww2[4];    // wiw gate biases for rows qd*4+r
#pragma unroll
  for (int r = 0; r < 4; ++r) {
    const float* wp = wiwb + (size_t)((qd * 4 + r) & 7) * 384 + h;
    ww0[r] = wp[0]; ww1[r] = wp[128]; ww2[r] = wp[256];
  }
  int sl_n2 = 0, cnt_n2 = 0;
  __syncthreads();  // LDS init visible (full sync once)

  for (int t = 0; t < CT; ++t) {
    const int par = t & 1;        // parity holding h_{t-2}; epilogue writes h_t here
    const int parp = par ^ 1;     // parity holding h_{t-1}

    // ---- S1': build A-frag in registers; publish h0 into Psg row 8 -------
    // Fresh rows (t-1 / t-2) from broadcast hbuf reads; older rows from the
    // prefetched hsb16 gather (rows <= t-2, store-visibility via barrier C).
    const bool f1 = (sl_c == t - 1), f2 = (sl_c == t - 2);
    short8 af[4];
#pragma unroll
    for (int kt = 0; kt < 4; ++kt) {
      short8 hA = *(const short8*)&hbuf[parp][kt * 32 + qd * 8];
      short8 hB = *(const short8*)&hbuf[par][kt * 32 + qd * 8];
      af[kt] = f1 ? hA : (f2 ? hB : af_g[kt]);
    }
    const float cbA = cbuf[parp][h], cbB = cbuf[par][h];
    if (wv == 7)  // Psg row 8 = h0 (= h_{t-1}); read+write ordered by barrier C/B
      *(u32*)&Psg[8 * 136 + 2 * ln] = *(const u32*)&hbuf[parp][2 * ln];

    // ---- S3: gw h-part = h_x @ w_hh_w (12 MFMA) --------------------------
    f32x4 d0 = {0.f, 0.f, 0.f, 0.f}, d1 = d0, d2 = d0;
#pragma unroll
    for (int kt = 0; kt < 4; ++kt) {
      d0 = mfma16(af[kt], wgwf[0][kt], d0);
      d1 = mfma16(af[kt], wgwf[1][kt], d1);
      d2 = mfma16(af[kt], wgwf[2][kt], d2);
    }
    // c1_skip: sw-part comes in as the precomputed wiw bias adds
    int srs[4];
#pragma unroll
    for (int r = 0; r < 4; ++r) srs[r] = __shfl(sl_c, (qd * 4 + r) & 7, 64);
    float c1s[4] = {0.f, 0.f, 0.f, 0.f};
    if (qd < 2) {  // rows 0..7 real
#pragma unroll
      for (int r = 0; r < 4; ++r) {
        const int rr = qd * 4 + r;
        const int sr = srs[r];
        const float cx = (sr == t - 1) ? cbA : (sr == t - 2) ? cbB : cg[r];
        const float fg = sigf(d0[r] + bw0 + ww0[r]);
        const float ig = sigf(d1[r] + bw1 + ww1[r]);
        const float gg = tanhfast(d2[r] + bw2 + ww2[r]);
        const float v = fg * cx + ig * gg;
        c1s[r] = v;
        Psg[rr * 136 + h] = f2b(v);
      }
    }

    // ---- prefetch for t+1 (after af_g/cg/ww consumed; single-buffered) ---
    const int tn = (t + 1 < CT) ? t + 1 : t;
    const int tn2 = (t + 2 < CT) ? t + 2 : CT - 1;
#pragma unroll
    for (int kt = 0; kt < 4; ++kt)
      af_g[kt] = *(const short8*)(hsb + (size_t)sl_n * CH + kt * 32 + qd * 8);
#pragma unroll
    for (int r = 0; r < 4; ++r) {
      int sr = __shfl(sl_n, (qd * 4 + r) & 7, 64);
      cg[r] = cs[(size_t)sr * CH + h];
    }
#pragma unroll
    for (int r = 0; r < 4; ++r) {
      const float* wp = wiwb + ((size_t)tn * CX + ((qd * 4 + r) & 7)) * 384 + h;
      ww0[r] = wp[0]; ww1[r] = wp[128]; ww2[r] = wp[256];
    }
    sl_n2 = srcb[tn2 * CX + row];
    cnt_n2 = cntb[tn2];

    barrier_lgkm();  // barrier B (LDS-only; all prefetch loads stay in flight)

    // ---- S5: [c1_skip; h0] @ [a_hh | w_hh_c] (16 MFMA), gates, softmax ---
    f32x4 e0 = {0.f, 0.f, 0.f, 0.f}, e1 = e0, e2 = e0, e3 = e0;
#pragma unroll
    for (int kt = 0; kt < 4; ++kt) {
      short8 a = *(const short8*)&Psg[l16 * 136 + kt * 32 + qd * 8];
      e0 = mfma16(a, wacf[0][kt], e0);
      e1 = mfma16(a, wacf[1][kt], e1);
      e2 = mfma16(a, wacf[2][kt], e2);
      e3 = mfma16(a, wacf[3][kt], e3);
    }
    // gc row (D row 8 = qd 2, reg 0) lives at lane 32+l16 (round-0-proven)
    const float gi_d = __shfl(e1[0], 32 + l16, 64);
    const float go_d = __shfl(e2[0], 32 + l16, 64);
    const float gg_d = __shfl(e3[0], 32 + l16, 64);
    const float i_g = sigf(gi_d + gt0);
    const float o_g = sigf(go_d + gt1);
    const float g_g = tanhfast(gg_d + gt2);
    float pe = 0.0f, pec = 0.0f;
#pragma unroll
    for (int r = 0; r < 4; ++r) {
      const int rr = qd * 4 + r;
      if (rr < cnt_c) {  // rows >= cnt masked; rows 8..15 auto-masked (cnt<=8)
        const float al = sigf(e0[r] + awi);
        const float e = __expf(al);
        pe += e;
        pec += e * c1s[r];
      }
    }
    pe += __shfl_xor(pe, 16, 64);  pec += __shfl_xor(pec, 16, 64);
    pe += __shfl_xor(pe, 32, 64);  pec += __shfl_xor(pec, 32, 64);
    const float ei = __expf(i_g);
    const float c1 = __fdividef(ei * g_g + pec, ei + pe);
    const float h1 = o_g * tanhfast(c1);

    // gate-bias prefetch for t+1 (after consumption; ~full step of lead)
    gt0 = wicab[(size_t)tn * 512 + h];
    gt1 = wicab[(size_t)tn * 512 + 128 + h];
    gt2 = wicab[(size_t)tn * 512 + 256 + h];
    awi = wicab[(size_t)tn * 512 + 384 + h];

    // ---- S6: epilogue ----------------------------------------------------
    if (qd == 0) {
      hs[(size_t)t * CH + h] = h1;
      cs[(size_t)t * CH + h] = c1;
      const u16 hb = f2b(h1);
      hsb[(size_t)t * CH + h] = hb;
      hbuf[par][h] = hb;
      cbuf[par][h] = c1;
    }
    barrier_vm20();  // barrier C: counted vmcnt (see comment at definition)

    sl_c = sl_n; sl_n = sl_n2; cnt_c = cnt_n; cnt_n = cnt_n2;
  }
}

// ===================== scan_kernel: R5 fallback (HW-proven) =================
__global__ __launch_bounds__(512, 2) void scan_kernel(
    const u16* __restrict__ swb16, const int* __restrict__ srcp,
    const int* __restrict__ cntp, const float* __restrict__ bias_w,
    const u16* __restrict__ WgwT, const u16* __restrict__ WahcT,
    const float* __restrict__ wica, float* __restrict__ out)
{
  const int b = blockIdx.x;
  const int tid = threadIdx.x;
  const int wv = tid >> 6;
  const int ln = tid & 63;
  const int l16 = ln & 15;
  const int qd = ln >> 4;
  const int h = wv * 16 + l16;

  float* hs = out + (size_t)b * CT * CH;
  float* cs = out + (size_t)(CB + b) * CT * CH;
  const u16* swb = swb16 + (size_t)b * CT * CX * CH;
  const int* srcb = srcp + b * CT * CX;
  const int* cntb = cntp + b * CT;
  const float* wicab = wica + (size_t)b * CT * 512;

  __shared__ __align__(16) u16 Asg[16 * 136];
  __shared__ __align__(16) u16 Psg[16 * 136];
  __shared__ __align__(16) float Csg[8 * 128];
  __shared__ __align__(16) u16 hbuf[2][128];
  __shared__ __align__(16) float cbuf[2][128];
  __shared__ float gca[512];

  for (int i = tid; i < 16 * 136; i += 512) { Asg[i] = 0; Psg[i] = 0; }
  if (tid < 128) {
    hbuf[0][tid] = 0; hbuf[1][tid] = 0;
    cbuf[0][tid] = 0.0f; cbuf[1][tid] = 0.0f;
  }

  short8 wgwf[3][8];
#pragma unroll
  for (int g = 0; g < 3; ++g) {
    const int n = g * 128 + h;
#pragma unroll
    for (int kt = 0; kt < 8; ++kt)
      wgwf[g][kt] = *(const short8*)(WgwT + (size_t)n * 256 + kt * 32 + qd * 8);
  }
  short8 wacf[4][4];
#pragma unroll
  for (int j = 0; j < 4; ++j) {
    const int n = j * 128 + h;
#pragma unroll
    for (int kt = 0; kt < 4; ++kt)
      wacf[j][kt] = *(const short8*)(WahcT + (size_t)n * 128 + kt * 32 + qd * 8);
  }
  const float bw0 = bias_w[h], bw1 = bias_w[128 + h], bw2 = bias_w[256 + h];

  const u16* swfbase = swb + (size_t)(l16 & 7) * CH + qd * 8;
  short8 swf[4];
#pragma unroll
  for (int kt = 0; kt < 4; ++kt)
    swf[kt] = *(const short8*)(swfbase + kt * 32);

  int src_c = srcb[wv];
  int cnt_c = cntb[0];
  int src_n = srcb[CX + wv];
  int cnt_n = cntb[1];
  float2 h2c, c2c;
  h2c = *(const float2*)(hs + (size_t)src_c * CH + 2 * ln);
  c2c = *(const float2*)(cs + (size_t)src_c * CH + 2 * ln);
  float wicac = wicab[tid];
  float2 h2n = {0.f, 0.f}, c2n = {0.f, 0.f};
  float wican = 0.f;
  int src_n2 = 0, cnt_n2 = 0;
  __syncthreads();

  for (int t = 0; t < CT; ++t) {
    const int par = t & 1;
    const int parp = par ^ 1;

    if (src_c == t - 1) {
      *(u32*)&Asg[wv * 136 + 2 * ln] = *(const u32*)&hbuf[parp][2 * ln];
      *(float2*)&Csg[wv * 128 + 2 * ln] = *(const float2*)&cbuf[parp][2 * ln];
    } else if (src_c == t - 2) {
      *(u32*)&Asg[wv * 136 + 2 * ln] = *(const u32*)&hbuf[par][2 * ln];
      *(float2*)&Csg[wv * 128 + 2 * ln] = *(const float2*)&cbuf[par][2 * ln];
    } else {
      *(u32*)&Asg[wv * 136 + 2 * ln] = (u32)f2b(h2c.x) | ((u32)f2b(h2c.y) << 16);
      *(float2*)&Csg[wv * 128 + 2 * ln] = c2c;
    }
    gca[tid] = wicac;
    if (wv == 7)
      *(u32*)&Asg[8 * 136 + 2 * ln] = *(const u32*)&hbuf[parp][2 * ln];
    barrier_lgkm();

    {
      const int tn = (t + 1 < CT) ? (t + 1) : t;
      const int tn2 = (t + 2 < CT) ? (t + 2) : (CT - 1);
      h2n = *(const float2*)(hs + (size_t)src_n * CH + 2 * ln);
      c2n = *(const float2*)(cs + (size_t)src_n * CH + 2 * ln);
      wican = wicab[(size_t)tn * 512 + tid];
      src_n2 = srcb[tn2 * CX + wv];
      cnt_n2 = cntb[tn2];
    }

    f32x4 d0 = {0.f, 0.f, 0.f, 0.f}, d1 = d0, d2 = d0;
    f32x4 e1 = d0, e2 = d0, e3 = d0;
#pragma unroll
    for (int kt = 0; kt < 4; ++kt) {
      short8 a = *(const short8*)&Asg[l16 * 136 + kt * 32 + qd * 8];
      d0 = mfma16(a, wgwf[0][kt], d0);
      d1 = mfma16(a, wgwf[1][kt], d1);
      d2 = mfma16(a, wgwf[2][kt], d2);
      e1 = mfma16(a, wacf[1][kt], e1);
      e2 = mfma16(a, wacf[2][kt], e2);
      e3 = mfma16(a, wacf[3][kt], e3);
    }
    {
      const int tn = (t + 1 < CT) ? (t + 1) : t;
      const u16* swfn = swfbase + (size_t)tn * CX * CH;
#pragma unroll
      for (int kt = 0; kt < 4; ++kt) {
        d0 = mfma16(swf[kt], wgwf[0][4 + kt], d0);
        d1 = mfma16(swf[kt], wgwf[1][4 + kt], d1);
        d2 = mfma16(swf[kt], wgwf[2][4 + kt], d2);
        swf[kt] = *(const short8*)(swfn + kt * 32);
      }
    }
    const float gi_d = __shfl(e1[0], 32 + l16, 64);
    const float go_d = __shfl(e2[0], 32 + l16, 64);
    const float gg_d = __shfl(e3[0], 32 + l16, 64);
    const float awi = gca[384 + h];
    const float i_g = sigf(gi_d + gca[h]);
    const float o_g = sigf(go_d + gca[128 + h]);
    const float g_g = tanhfast(gg_d + gca[256 + h]);

    float c1s[4] = {0.f, 0.f, 0.f, 0.f};
    if (qd < 2) {
#pragma unroll
      for (int r = 0; r < 4; ++r) {
        const int row = qd * 4 + r;
        const float cx = Csg[row * 128 + h];
        const float fg = sigf(d0[r] + bw0);
        const float ig = sigf(d1[r] + bw1);
        const float gg = tanhfast(d2[r] + bw2);
        const float v = fg * cx + ig * gg;
        c1s[r] = v;
        Psg[row * 136 + h] = f2b(v);
      }
    }
    barrier_lgkm();

    f32x4 e0 = {0.f, 0.f, 0.f, 0.f};
#pragma unroll
    for (int kt = 0; kt < 4; ++kt) {
      short8 a = *(const short8*)&Psg[l16 * 136 + kt * 32 + qd * 8];
      e0 = mfma16(a, wacf[0][kt], e0);
    }
    float pe = 0.0f, pec = 0.0f;
#pragma unroll
    for (int r = 0; r < 4; ++r) {
      const int row = qd * 4 + r;
      if (row < cnt_c) {
        const float al = sigf(e0[r] + awi);
        const float e = __expf(al);
        pe += e;
        pec += e * c1s[r];
      }
    }
    pe += __shfl_xor(pe, 16, 64);  pec += __shfl_xor(pec, 16, 64);
    pe += __shfl_xor(pe, 32, 64);  pec += __shfl_xor(pec, 32, 64);
    const float ei = __expf(i_g);
    const float c1 = __fdividef(ei * g_g + pec, ei + pe);
    const float h1 = o_g * tanhfast(c1);

    if (qd == 0) {
      hs[(size_t)t * CH + h] = h1;
      cs[(size_t)t * CH + h] = c1;
      hbuf[par][h] = f2b(h1);
      cbuf[par][h] = c1;
    }
    barrier_vm8();

    h2c = h2n; c2c = c2n; wicac = wican;
    src_c = src_n; cnt_c = cnt_n; src_n = src_n2; cnt_n = cnt_n2;
  }
}

extern "C" void kernel_launch(void* const* d_in, const int* in_sizes, int n_in,
                              void* d_out, int out_size, void* d_ws, size_t ws_size,
                              hipStream_t stream) {
  (void)in_sizes; (void)n_in; (void)out_size;
  const float* inp    = (const float*)d_in[0];
  const float* skw    = (const float*)d_in[1];
  const int*   ssrc   = (const int*)d_in[3];
  const int*   scnt   = (const int*)d_in[4];
  const float* w_ih_c = (const float*)d_in[5];
  const float* w_hh_c = (const float*)d_in[6];
  const float* bias_c = (const float*)d_in[7];
  const float* a_ih   = (const float*)d_in[8];
  const float* a_hh   = (const float*)d_in[9];
  const float* a_bias = (const float*)d_in[10];
  const float* w_ih_w = (const float*)d_in[11];
  const float* w_hh_w = (const float*)d_in[12];
  const float* bias_w = (const float*)d_in[13];

  char* ws = (char*)d_ws;
  u16*   WgwT  = (u16*)(ws);
  u16*   WahcT = (u16*)(ws + 196608);
  u16*   WcaT  = (u16*)(ws + 327680);
  float* wica  = (float*)(ws + 458752);
  float* out   = (float*)d_out;

  prep_kernel<<<224, 1024, 0, stream>>>(w_ih_c, w_hh_c, a_ih, a_hh, w_ih_w, w_hh_w,
                                        WgwT, WahcT, WcaT);
  proj_kernel<<<512, 256, 0, stream>>>(inp, WcaT, bias_c, a_bias, wica);

  const size_t NEED_V2 = 458752ull + 67108864ull + 402653184ull + 8388608ull;  // 478609408
  if (ws_size >= NEED_V2) {
    float* wiw   = (float*)(ws + 67567616);
    u16*   hsb16 = (u16*)(ws + 470220800);
    wiw_kernel<<<4096, 256, 0, stream>>>(skw, WgwT, wiw);
    scan_v2<<<64, 512, 0, stream>>>(ssrc, scnt, bias_w, WgwT, WahcT, wica, wiw,
                                    hsb16, out);
  } else {
    u16* swb16 = (u16*)(ws + 67567616);
    prep_sw_kernel<<<4096, 1024, 0, stream>>>(skw, swb16);
    scan_kernel<<<64, 512, 0, stream>>>(swb16, ssrc, scnt, bias_w, WgwT, WahcT,
                                        wica, out);
  }
}